// Round 4
// baseline (1242.319 us; speedup 1.0000x reference)
//
#include <hip/hip_runtime.h>

#define HIDDEN 2048
#define EXPERTS 64
#define T_TOTAL 8192

// ================= GEMM: split-K, LDS-tiled, lane = expert =================
// BM=32 rows/block, BK=64 k/tile. 4 waves: wave w -> rows [8w, 8w+8), lane = expert.
// A LDS reads are wave-broadcast (same addr, conflict-free, NO padding needed);
// W LDS reads are 64 consecutive words (2-way aliasing = free).
#define BM 32
#define BK 64

__global__ __launch_bounds__(256, 2) void snn_gemm_sk(
        const float* __restrict__ A, const float* __restrict__ W,
        float* __restrict__ P, int KS) {
    __shared__ float As[2][BM * BK];        // 2 x 8 KB
    __shared__ float Ws[2][BK * EXPERTS];   // 2 x 16 KB

    const int t    = threadIdx.x;
    const int lane = t & 63;
    const int wv   = t >> 6;
    const long row0 = (long)blockIdx.x * BM;
    const int  k0   = blockIdx.y * KS;
    float* Pout = P + (long)blockIdx.y * ((long)T_TOTAL * EXPERTS);

    const int srow = t >> 4;     // 0..15 staging row
    const int skq  = t & 15;     // 0..15 staging float4 col

    float acc[8];
#pragma unroll
    for (int r = 0; r < 8; ++r) acc[r] = 0.0f;

    float4 ar[2], wr[4];

    auto load_tile = [&](int kt) {
        // A tile: 32 rows x 64 floats; round p covers rows p*16 .. p*16+15
#pragma unroll
        for (int p = 0; p < 2; ++p)
            ar[p] = *reinterpret_cast<const float4*>(
                &A[(row0 + p * 16 + srow) * HIDDEN + kt + skq * 4]);
        // W tile: 64 rows x 64 floats, linear float4 index
#pragma unroll
        for (int p = 0; p < 4; ++p) {
            const int fid = t + 256 * p;                       // 0..1023
            wr[p] = *reinterpret_cast<const float4*>(
                &W[(long)(kt + (fid >> 4)) * EXPERTS + (fid & 15) * 4]);
        }
    };
    auto write_tile = [&](int buf) {
#pragma unroll
        for (int p = 0; p < 2; ++p)
            *reinterpret_cast<float4*>(&As[buf][(p * 16 + srow) * BK + skq * 4]) = ar[p];
#pragma unroll
        for (int p = 0; p < 4; ++p)
            *reinterpret_cast<float4*>(&Ws[buf][(t + 256 * p) * 4]) = wr[p];
    };

    load_tile(k0);
    write_tile(0);
    __syncthreads();

    const int ntile = KS / BK;
    for (int tile = 0; tile < ntile; ++tile) {
        const int buf = tile & 1;
        if (tile + 1 < ntile) load_tile(k0 + (tile + 1) * BK);   // issue early (T14)

        const float* ab = &As[buf][wv * 8 * BK];
        const float* wb = &Ws[buf][0];
#pragma unroll
        for (int q = 0; q < BK / 4; ++q) {
            float4 a4[8];
#pragma unroll
            for (int r = 0; r < 8; ++r)
                a4[r] = *reinterpret_cast<const float4*>(&ab[r * BK + q * 4]);
            float wk[4];
#pragma unroll
            for (int ki = 0; ki < 4; ++ki)
                wk[ki] = wb[(q * 4 + ki) * EXPERTS + lane];
            // ascending k within each acc -> deterministic summation order
#pragma unroll
            for (int r = 0; r < 8; ++r) {
                acc[r] = fmaf(a4[r].x, wk[0], acc[r]);
                acc[r] = fmaf(a4[r].y, wk[1], acc[r]);
                acc[r] = fmaf(a4[r].z, wk[2], acc[r]);
                acc[r] = fmaf(a4[r].w, wk[3], acc[r]);
            }
        }
        if (tile + 1 < ntile) write_tile(buf ^ 1);   // vmcnt wait sits after compute
        __syncthreads();
    }

#pragma unroll
    for (int r = 0; r < 8; ++r)
        Pout[(row0 + wv * 8 + r) * EXPERTS + lane] = acc[r];
}

// ---- fixed-order split-K combine: cur = ((p0+p1)+p2)+... ----
__global__ __launch_bounds__(256) void snn_combine(const float* __restrict__ P,
                                                   float* __restrict__ cur, int nsplit) {
    const long i = (long)blockIdx.x * 256 + threadIdx.x;   // float4 index
    const float4* p = reinterpret_cast<const float4*>(P);
    float4 s = p[i];
    for (int k = 1; k < nsplit; ++k) {
        const float4 v = p[i + (long)k * (T_TOTAL * EXPERTS / 4)];
        s.x += v.x; s.y += v.y; s.z += v.z; s.w += v.w;
    }
    reinterpret_cast<float4*>(cur)[i] = s;
}

// ================= Scan: waveform relaxation, 32 chunks x 256 steps =================
#define NCHUNK 32
#define CSTEPS (T_TOTAL / NCHUNK)   // 256
#define KITER  4
#define PF     32

__global__ __launch_bounds__(64) void snn_scan_wfr(const float* __restrict__ cur,
                                                   float* __restrict__ mp_out,
                                                   float* __restrict__ states,
                                                   int* __restrict__ flags) {
#pragma clang fp contract(off)
    __shared__ float smp[CSTEPS * EXPERTS];   // 64 KB
    const int e = threadIdx.x;
    const int w = blockIdx.x;
    const float* cbase = cur + (long)w * CSTEPS * EXPERTS + e;

    for (int k = 1; k <= KITER; ++k) {
        float mp = 0.0f, refr = 0.0f;
        if (w > 0 && k > 1) {
            const int s = (k - 2) * NCHUNK + (w - 1);
            if (e == 0) {
                while (__hip_atomic_load(&flags[s], __ATOMIC_ACQUIRE, __HIP_MEMORY_SCOPE_AGENT) == 0)
                    __builtin_amdgcn_s_sleep(8);
            }
            __threadfence();
            mp   = __hip_atomic_load(&states[s * 2 * EXPERTS + e], __ATOMIC_RELAXED, __HIP_MEMORY_SCOPE_AGENT);
            refr = __hip_atomic_load(&states[s * 2 * EXPERTS + EXPERTS + e], __ATOMIC_RELAXED, __HIP_MEMORY_SCOPE_AGENT);
        }

        float ca[PF], cb[PF];
#pragma unroll
        for (int j = 0; j < PF; ++j) ca[j] = cbase[j * EXPERTS] * 0.1f;

        for (int t0 = 0; t0 < CSTEPS; t0 += 2 * PF) {
#pragma unroll
            for (int j = 0; j < PF; ++j) cb[j] = cbase[(t0 + PF + j) * EXPERTS] * 0.1f;
#pragma unroll
            for (int j = 0; j < PF; ++j) {
                const float term   = (refr <= 0.0f) ? ca[j] : 0.0f;
                const float mp_pre = mp * 0.9f + term;
                smp[(t0 + j) * EXPERTS + e] = mp_pre;
                const bool spike = mp_pre > 1.0f;
                mp = spike ? 0.0f : mp_pre;
                const float rdec = fmaxf(refr - 0.1f, 0.0f);
                refr = spike ? 1.0f : rdec;
            }
            if (t0 + 2 * PF < CSTEPS) {
#pragma unroll
                for (int j = 0; j < PF; ++j) ca[j] = cbase[(t0 + 2 * PF + j) * EXPERTS] * 0.1f;
            }
#pragma unroll
            for (int j = 0; j < PF; ++j) {
                const float term   = (refr <= 0.0f) ? cb[j] : 0.0f;
                const float mp_pre = mp * 0.9f + term;
                smp[(t0 + PF + j) * EXPERTS + e] = mp_pre;
                const bool spike = mp_pre > 1.0f;
                mp = spike ? 0.0f : mp_pre;
                const float rdec = fmaxf(refr - 0.1f, 0.0f);
                refr = spike ? 1.0f : rdec;
            }
        }

        if (k < KITER && w < NCHUNK - 1) {
            const int s2 = (k - 1) * NCHUNK + w;
            __hip_atomic_store(&states[s2 * 2 * EXPERTS + e], mp, __ATOMIC_RELAXED, __HIP_MEMORY_SCOPE_AGENT);
            __hip_atomic_store(&states[s2 * 2 * EXPERTS + EXPERTS + e], refr, __ATOMIC_RELAXED, __HIP_MEMORY_SCOPE_AGENT);
            __threadfence();
            if (e == 0)
                __hip_atomic_store(&flags[s2], 1, __ATOMIC_RELEASE, __HIP_MEMORY_SCOPE_AGENT);
        }
    }

    float4* o4 = reinterpret_cast<float4*>(mp_out + (long)w * CSTEPS * EXPERTS);
    const float4* s4 = reinterpret_cast<const float4*>(smp);
#pragma unroll 4
    for (int i = threadIdx.x; i < CSTEPS * EXPERTS / 4; i += 64)
        o4[i] = s4[i];
}

// ================= Routing softmax (in-place on d_out) =================
__global__ __launch_bounds__(256) void snn_softmax(float* __restrict__ io) {
    const int  lane = threadIdx.x & 63;
    const int  wv   = threadIdx.x >> 6;
    const long t    = (long)blockIdx.x * 4 + wv;

    const float v = io[t * EXPERTS + lane];
    const bool spike = v > 1.0f;
    const unsigned long long ball = __ballot(spike);

    float out;
    if (ball != 0ull) {
        const int   n   = __popcll(ball);
        const float em1 = expf(-1.0f);
        const float denom = (float)n + (float)(EXPERTS - n) * em1;
        out = spike ? (1.0f / denom) : (em1 / denom);
    } else {
        float m = v;
#pragma unroll
        for (int off = 32; off >= 1; off >>= 1)
            m = fmaxf(m, __shfl_xor(m, off, 64));
        const float p = expf(v - m);
        float s = p;
#pragma unroll
        for (int off = 32; off >= 1; off >>= 1)
            s += __shfl_xor(s, off, 64);
        out = p / s;
    }
    io[t * EXPERTS + lane] = out;
}

// ---------------------------------------------------------------------------
extern "C" void kernel_launch(void* const* d_in, const int* in_sizes, int n_in,
                              void* d_out, int out_size, void* d_ws, size_t ws_size,
                              hipStream_t stream) {
    const float* hs = (const float*)d_in[0];   // [4,2048,2048] f32
    const float* w  = (const float*)d_in[1];   // [2048,64] f32
    float* out = (float*)d_out;                // [4,2048,64] f32

    char*  ws     = (char*)d_ws;
    int*   flags  = (int*)ws;                          // 4 KB
    float* states = (float*)(ws + 4096);               // 64 KB
    float* cur    = (float*)(ws + (1u << 20));         // 2 MB  @ 1 MB
    float* part   = (float*)(ws + (4u << 20));         // nsplit*2 MB @ 4 MB

    const size_t slab = (size_t)T_TOTAL * EXPERTS * sizeof(float);   // 2 MB
    int nsplit;
    if      (ws_size >= (4u << 20) + 4 * slab) nsplit = 4;   // 12 MB
    else if (ws_size >= (4u << 20) + 2 * slab) nsplit = 2;   // 8 MB
    else                                       nsplit = 1;

    hipMemsetAsync(flags, 0, 4096, stream);

    if (nsplit == 1) {
        snn_gemm_sk<<<dim3(T_TOTAL / BM, 1), dim3(256), 0, stream>>>(hs, w, cur, HIDDEN);
    } else {
        snn_gemm_sk<<<dim3(T_TOTAL / BM, nsplit), dim3(256), 0, stream>>>(hs, w, part, HIDDEN / nsplit);
        snn_combine<<<dim3(T_TOTAL * EXPERTS / 4 / 256), dim3(256), 0, stream>>>(part, cur, nsplit);
    }
    snn_scan_wfr<<<dim3(NCHUNK), dim3(64), 0, stream>>>(cur, out, states, flags);
    snn_softmax<<<dim3(T_TOTAL / 4), dim3(256), 0, stream>>>(out);
}

// Round 5
// 122.376 us; speedup vs baseline: 10.1517x; 10.1517x over previous
//
#include <hip/hip_runtime.h>
#include <stdint.h>

#define HIDDEN 2048
#define EXPERTS 64
#define T_TOTAL 8192

// ================= GEMM: split-K, global_load_lds-staged, lane = expert =================
// BM=32 rows, BK=32 k per tile. 4 waves; wave wv computes rows [wv*8, wv*8+8), lane = expert.
// A LDS reads: wave-broadcast (same addr) -> conflict-free, no padding.
// W LDS reads: lane-consecutive words -> 2-way aliasing = free. (R4 measured 0 conflicts.)
// Staging: pure global_load_lds dwordx4, LDS dst == wave-uniform base + lane*16 by construction.
#define BM 32
#define BK 32
#define NSPLIT 4

#define GLOAD16(g, l) __builtin_amdgcn_global_load_lds(                        \
        (const __attribute__((address_space(1))) unsigned int*)(g),            \
        (__attribute__((address_space(3))) unsigned int*)(l), 16, 0, 0)
#define FENCE() asm volatile("" ::: "memory")

template <int KS>
__global__ __launch_bounds__(256) void snn_gemm_sk(
        const float* __restrict__ A, const float* __restrict__ W,
        float* __restrict__ P) {
    __shared__ float As[2][BM * BK];        // 2 x 4 KB
    __shared__ float Ws[2][BK * EXPERTS];   // 2 x 8 KB

    const int t    = threadIdx.x;
    const int lane = t & 63;
    const int wv   = t >> 6;
    const long row0 = (long)blockIdx.x * BM;
    const int  k0   = blockIdx.y * KS;
    float* Pout = P + (long)blockIdx.y * ((long)T_TOTAL * EXPERTS);

    // --- staging geometry (per wave: contiguous 1024B chunks, lane*16 within chunk) ---
    // A tile chunk wv: tile byte = wv*1024 + lane*16  ->  row = wv*8 + lane/8, kword = (lane&7)*4
    const int arow = wv * 8 + (lane >> 3);
    const int acol = (lane & 7) * 4;
    const float* aSrcBase = &A[(row0 + arow) * HIDDEN + acol];   // + kt
    // W tile chunks c = wv, wv+4: tile byte = c*1024 + lane*16 -> k = c*4 + lane/16, e = (lane&15)*4
    const int wk0 = (lane >> 4);
    const int we0 = (lane & 15) * 4;

    auto stage = [&](int kt, int buf) {
        GLOAD16(aSrcBase + kt, &As[buf][wv * 8 * BK + acol + (lane >> 3) * BK]);
        GLOAD16(&W[(long)(kt + wv * 4 + wk0) * EXPERTS + we0],
                &Ws[buf][(wv * 4 + wk0) * EXPERTS + we0]);
        GLOAD16(&W[(long)(kt + (wv + 4) * 4 + wk0) * EXPERTS + we0],
                &Ws[buf][((wv + 4) * 4 + wk0) * EXPERTS + we0]);
    };

    float acc[8];
#pragma unroll
    for (int r = 0; r < 8; ++r) acc[r] = 0.0f;

    stage(k0, 0);

    const int ntile = KS / BK;
    int buf = 0;
    for (int tile = 0; tile < ntile; ++tile) {
        if (tile + 1 < ntile) {
            stage(k0 + (tile + 1) * BK, buf ^ 1);
            asm volatile("s_waitcnt vmcnt(3)" ::: "memory");   // current tile landed; next stays in flight
        } else {
            asm volatile("s_waitcnt vmcnt(0)" ::: "memory");
        }
        __builtin_amdgcn_s_barrier();
        FENCE();

        const float* ab = &As[buf][wv * 8 * BK];
        const float* wb = &Ws[buf][0];
#pragma unroll
        for (int q = 0; q < BK / 4; ++q) {
            float wk[4];
#pragma unroll
            for (int ki = 0; ki < 4; ++ki)
                wk[ki] = wb[(q * 4 + ki) * EXPERTS + lane];
            float4 a4;
#pragma unroll
            for (int r = 0; r < 8; ++r) {
                a4 = *reinterpret_cast<const float4*>(&ab[r * BK + q * 4]);
                acc[r] = fmaf(a4.x, wk[0], acc[r]);
                acc[r] = fmaf(a4.y, wk[1], acc[r]);
                acc[r] = fmaf(a4.z, wk[2], acc[r]);
                acc[r] = fmaf(a4.w, wk[3], acc[r]);
            }
        }
        FENCE();
        __builtin_amdgcn_s_barrier();   // all waves done reading buf before it is restaged
        buf ^= 1;
    }

#pragma unroll
    for (int r = 0; r < 8; ++r)
        Pout[(row0 + wv * 8 + r) * EXPERTS + lane] = acc[r];
}

// ---- fixed-order split-K combine: cur = ((p0+p1)+p2)+p3 ----
__global__ __launch_bounds__(256) void snn_combine(const float* __restrict__ P,
                                                   float* __restrict__ cur, int nsplit) {
    const long i = (long)blockIdx.x * 256 + threadIdx.x;   // float4 index
    const float4* p = reinterpret_cast<const float4*>(P);
    float4 s = p[i];
    for (int k = 1; k < nsplit; ++k) {
        const float4 v = p[i + (long)k * (T_TOTAL * EXPERTS / 4)];
        s.x += v.x; s.y += v.y; s.z += v.z; s.w += v.w;
    }
    reinterpret_cast<float4*>(cur)[i] = s;
}

// ================= Scan: waveform relaxation, 32 chunks x 256 steps =================
#define NCHUNK 32
#define CSTEPS (T_TOTAL / NCHUNK)   // 256
#define KITER  4
#define PF     32

__global__ __launch_bounds__(64) void snn_scan_wfr(const float* __restrict__ cur,
                                                   float* __restrict__ mp_out,
                                                   float* __restrict__ states,
                                                   int* __restrict__ flags) {
#pragma clang fp contract(off)
    __shared__ float smp[CSTEPS * EXPERTS];   // 64 KB
    const int e = threadIdx.x;
    const int w = blockIdx.x;
    const float* cbase = cur + (long)w * CSTEPS * EXPERTS + e;

    for (int k = 1; k <= KITER; ++k) {
        float mp = 0.0f, refr = 0.0f;
        if (w > 0 && k > 1) {
            const int s = (k - 2) * NCHUNK + (w - 1);
            if (e == 0) {
                while (__hip_atomic_load(&flags[s], __ATOMIC_ACQUIRE, __HIP_MEMORY_SCOPE_AGENT) == 0)
                    __builtin_amdgcn_s_sleep(8);
            }
            __threadfence();
            mp   = __hip_atomic_load(&states[s * 2 * EXPERTS + e], __ATOMIC_RELAXED, __HIP_MEMORY_SCOPE_AGENT);
            refr = __hip_atomic_load(&states[s * 2 * EXPERTS + EXPERTS + e], __ATOMIC_RELAXED, __HIP_MEMORY_SCOPE_AGENT);
        }

        float ca[PF], cb[PF];
#pragma unroll
        for (int j = 0; j < PF; ++j) ca[j] = cbase[j * EXPERTS] * 0.1f;

        for (int t0 = 0; t0 < CSTEPS; t0 += 2 * PF) {
#pragma unroll
            for (int j = 0; j < PF; ++j) cb[j] = cbase[(t0 + PF + j) * EXPERTS] * 0.1f;
#pragma unroll
            for (int j = 0; j < PF; ++j) {
                const float term   = (refr <= 0.0f) ? ca[j] : 0.0f;
                const float mp_pre = mp * 0.9f + term;
                smp[(t0 + j) * EXPERTS + e] = mp_pre;
                const bool spike = mp_pre > 1.0f;
                mp = spike ? 0.0f : mp_pre;
                const float rdec = fmaxf(refr - 0.1f, 0.0f);
                refr = spike ? 1.0f : rdec;
            }
            if (t0 + 2 * PF < CSTEPS) {
#pragma unroll
                for (int j = 0; j < PF; ++j) ca[j] = cbase[(t0 + 2 * PF + j) * EXPERTS] * 0.1f;
            }
#pragma unroll
            for (int j = 0; j < PF; ++j) {
                const float term   = (refr <= 0.0f) ? cb[j] : 0.0f;
                const float mp_pre = mp * 0.9f + term;
                smp[(t0 + PF + j) * EXPERTS + e] = mp_pre;
                const bool spike = mp_pre > 1.0f;
                mp = spike ? 0.0f : mp_pre;
                const float rdec = fmaxf(refr - 0.1f, 0.0f);
                refr = spike ? 1.0f : rdec;
            }
        }

        if (k < KITER && w < NCHUNK - 1) {
            const int s2 = (k - 1) * NCHUNK + w;
            __hip_atomic_store(&states[s2 * 2 * EXPERTS + e], mp, __ATOMIC_RELAXED, __HIP_MEMORY_SCOPE_AGENT);
            __hip_atomic_store(&states[s2 * 2 * EXPERTS + EXPERTS + e], refr, __ATOMIC_RELAXED, __HIP_MEMORY_SCOPE_AGENT);
            __threadfence();
            if (e == 0)
                __hip_atomic_store(&flags[s2], 1, __ATOMIC_RELEASE, __HIP_MEMORY_SCOPE_AGENT);
        }
    }

    float4* o4 = reinterpret_cast<float4*>(mp_out + (long)w * CSTEPS * EXPERTS);
    const float4* s4 = reinterpret_cast<const float4*>(smp);
#pragma unroll 4
    for (int i = threadIdx.x; i < CSTEPS * EXPERTS / 4; i += 64)
        o4[i] = s4[i];
}

// ================= Routing softmax (in-place on d_out) =================
__global__ __launch_bounds__(256) void snn_softmax(float* __restrict__ io) {
    const int  lane = threadIdx.x & 63;
    const int  wv   = threadIdx.x >> 6;
    const long t    = (long)blockIdx.x * 4 + wv;

    const float v = io[t * EXPERTS + lane];
    const bool spike = v > 1.0f;
    const unsigned long long ball = __ballot(spike);

    float out;
    if (ball != 0ull) {
        const int   n   = __popcll(ball);
        const float em1 = expf(-1.0f);
        const float denom = (float)n + (float)(EXPERTS - n) * em1;
        out = spike ? (1.0f / denom) : (em1 / denom);
    } else {
        float m = v;
#pragma unroll
        for (int off = 32; off >= 1; off >>= 1)
            m = fmaxf(m, __shfl_xor(m, off, 64));
        const float p = expf(v - m);
        float s = p;
#pragma unroll
        for (int off = 32; off >= 1; off >>= 1)
            s += __shfl_xor(s, off, 64);
        out = p / s;
    }
    io[t * EXPERTS + lane] = out;
}

// ---------------------------------------------------------------------------
extern "C" void kernel_launch(void* const* d_in, const int* in_sizes, int n_in,
                              void* d_out, int out_size, void* d_ws, size_t ws_size,
                              hipStream_t stream) {
    const float* hs = (const float*)d_in[0];   // [4,2048,2048] f32
    const float* w  = (const float*)d_in[1];   // [2048,64] f32
    float* out = (float*)d_out;                // [4,2048,64] f32

    char*  ws     = (char*)d_ws;
    int*   flags  = (int*)ws;                          // 4 KB
    float* states = (float*)(ws + 4096);               // 64 KB
    float* cur    = (float*)(ws + (1u << 20));         // 2 MB @ 1 MB
    float* part   = (float*)(ws + (4u << 20));         // 4 x 2 MB @ 4 MB

    const size_t slab = (size_t)T_TOTAL * EXPERTS * sizeof(float);   // 2 MB
    const bool can_split = ws_size >= (4u << 20) + NSPLIT * slab;    // 12 MB

    hipMemsetAsync(flags, 0, 4096, stream);

    if (can_split) {
        snn_gemm_sk<HIDDEN / NSPLIT><<<dim3(T_TOTAL / BM, NSPLIT), dim3(256), 0, stream>>>(hs, w, part);
        snn_combine<<<dim3(T_TOTAL * EXPERTS / 4 / 256), dim3(256), 0, stream>>>(part, cur, NSPLIT);
    } else {
        snn_gemm_sk<HIDDEN><<<dim3(T_TOTAL / BM, 1), dim3(256), 0, stream>>>(hs, w, cur);
    }
    snn_scan_wfr<<<dim3(NCHUNK), dim3(64), 0, stream>>>(cur, out, states, flags);
    snn_softmax<<<dim3(T_TOTAL / 4), dim3(256), 0, stream>>>(out);
}

// Round 6
// 88.242 us; speedup vs baseline: 14.0785x; 1.3868x over previous
//
#include <hip/hip_runtime.h>
#include <stdint.h>

#define HIDDEN 2048
#define EXPERTS 64
#define T_TOTAL 8192

// ================= GEMM: split-K, global_load_lds staged, 4x8 micro-tile =================
// Block: 256 thr, BM=128 rows x 64 experts. Thread: rg=t>>3 -> rows rg*4..+3, eg=t&7 ->
// experts eg*8..+7. Per q-step: 4 A b128 + 8 W b128 feed 128 fma (10.7 fma/LDS-read).
// A tile XOR-swizzled (colblk ^= (row>>2)&7) on BOTH sides (pre-swizzled gload src +
// swizzled ds_read) -> 8 distinct banks {0,4..28}, conflict-free.
// W tile linear [k][e]: 8 distinct addrs, 2 per bank-pair -> 2-way = free.
#define BM 128
#define BK 32
#define NSPLIT 8

#define GLOAD16(g, l) __builtin_amdgcn_global_load_lds(                        \
        (const __attribute__((address_space(1))) unsigned int*)(g),            \
        (__attribute__((address_space(3))) unsigned int*)(l), 16, 0, 0)
#define FENCE() asm volatile("" ::: "memory")

template <int KS>
__global__ __launch_bounds__(256) void snn_gemm_sk(
        const float* __restrict__ A, const float* __restrict__ W,
        float* __restrict__ P) {
    __shared__ float As[2][BM * BK];        // 2 x 16 KB
    __shared__ float Ws[2][BK * EXPERTS];   // 2 x 8 KB

    const int t    = threadIdx.x;
    const int lane = t & 63;
    const int wv   = t >> 6;
    const int rg   = t >> 3;      // 0..31: rows rg*4..rg*4+3
    const int eg   = t & 7;       // 0..7 : experts eg*8..eg*8+7
    const long row0 = (long)blockIdx.x * BM;
    const int  k0   = blockIdx.y * KS;
    float* Pout = P + (long)blockIdx.y * ((long)T_TOTAL * EXPERTS);

    // ---- staging geometry ----
    // A: 4 rounds of 256 lanes x 16B. Linear LDS word o=(p*256+wv*64+lane)*4:
    //   row = p*32 + wv*8 + (lane>>3), colblk16 = lane&7. Stored value must be
    //   A[row][colblk ^ ((row>>2)&7)] -> pre-swizzle the GLOBAL source.
    const int l3 = lane >> 3, l7 = lane & 7;
    const float* aSrc[4];
#pragma unroll
    for (int p = 0; p < 4; ++p) {
        const int row = p * 32 + wv * 8 + l3;
        const int cb  = l7 ^ ((row >> 2) & 7);
        aSrc[p] = &A[(row0 + row) * HIDDEN + k0 + cb * 4];
    }
    // W: 2 rounds. word o=(p*256+wv*64+lane)*4: k = p*16+wv*4+(lane>>4), e4 = lane&15.
    const float* wSrc[2];
#pragma unroll
    for (int p = 0; p < 2; ++p) {
        const int k = p * 16 + wv * 4 + (lane >> 4);
        wSrc[p] = &W[(long)(k0 + k) * EXPERTS + (lane & 15) * 4];
    }

    auto stage = [&](int tile, int buf) {
        const int  aoff = tile * BK;
        const long woff = (long)tile * BK * EXPERTS;
#pragma unroll
        for (int p = 0; p < 4; ++p)
            GLOAD16(aSrc[p] + aoff, &As[buf][p * 1024 + wv * 256]);   // +lane*16B by HW
#pragma unroll
        for (int p = 0; p < 2; ++p)
            GLOAD16(wSrc[p] + woff, &Ws[buf][p * 1024 + wv * 256]);
    };

    float acc[4][8];
#pragma unroll
    for (int i = 0; i < 4; ++i)
#pragma unroll
        for (int j = 0; j < 8; ++j) acc[i][j] = 0.0f;

    stage(0, 0);

    constexpr int NTILE = KS / BK;
    int buf = 0;
    for (int tile = 0; tile < NTILE; ++tile) {
        if (tile + 1 < NTILE) {
            stage(tile + 1, buf ^ 1);
            asm volatile("s_waitcnt vmcnt(6)" ::: "memory");   // current landed; next 6 in flight
        } else {
            asm volatile("s_waitcnt vmcnt(0)" ::: "memory");
        }
        __builtin_amdgcn_s_barrier();
        FENCE();

        const float* ab = &As[buf][0];
        const float* wb = &Ws[buf][0];
        const int swz = rg & 7;
#pragma unroll
        for (int q = 0; q < BK / 4; ++q) {
            const int qs = (q ^ swz) * 4;
            float4 a4[4];
#pragma unroll
            for (int i = 0; i < 4; ++i)
                a4[i] = *reinterpret_cast<const float4*>(&ab[(rg * 4 + i) * BK + qs]);
#pragma unroll
            for (int ki = 0; ki < 4; ++ki) {
                const float4 w0 = *reinterpret_cast<const float4*>(&wb[(q * 4 + ki) * EXPERTS + eg * 8]);
                const float4 w1 = *reinterpret_cast<const float4*>(&wb[(q * 4 + ki) * EXPERTS + eg * 8 + 4]);
#pragma unroll
                for (int i = 0; i < 4; ++i) {
                    const float av = (&a4[i].x)[ki];   // k ascending: q outer, ki inner
                    acc[i][0] = fmaf(av, w0.x, acc[i][0]);
                    acc[i][1] = fmaf(av, w0.y, acc[i][1]);
                    acc[i][2] = fmaf(av, w0.z, acc[i][2]);
                    acc[i][3] = fmaf(av, w0.w, acc[i][3]);
                    acc[i][4] = fmaf(av, w1.x, acc[i][4]);
                    acc[i][5] = fmaf(av, w1.y, acc[i][5]);
                    acc[i][6] = fmaf(av, w1.z, acc[i][6]);
                    acc[i][7] = fmaf(av, w1.w, acc[i][7]);
                }
            }
        }
        FENCE();
        __builtin_amdgcn_s_barrier();   // all waves done with buf^1 before restage
        buf ^= 1;
    }

#pragma unroll
    for (int i = 0; i < 4; ++i) {
        float* base = &Pout[(row0 + rg * 4 + i) * EXPERTS + eg * 8];
        *reinterpret_cast<float4*>(base)     = make_float4(acc[i][0], acc[i][1], acc[i][2], acc[i][3]);
        *reinterpret_cast<float4*>(base + 4) = make_float4(acc[i][4], acc[i][5], acc[i][6], acc[i][7]);
    }
}

// ---- fixed-order split-K combine: cur = (((p0+p1)+p2)+...) ----
__global__ __launch_bounds__(256) void snn_combine(const float* __restrict__ P,
                                                   float* __restrict__ cur, int nsplit) {
    const long i = (long)blockIdx.x * 256 + threadIdx.x;   // float4 index
    const float4* p = reinterpret_cast<const float4*>(P);
    float4 s = p[i];
    for (int k = 1; k < nsplit; ++k) {
        const float4 v = p[i + (long)k * (T_TOTAL * EXPERTS / 4)];
        s.x += v.x; s.y += v.y; s.z += v.z; s.w += v.w;
    }
    reinterpret_cast<float4*>(cur)[i] = s;
}

// ================= Scan: waveform relaxation, 32 chunks x 256 steps =================
#define NCHUNK 32
#define CSTEPS (T_TOTAL / NCHUNK)   // 256
#define KITER  4
#define PF     32

__global__ __launch_bounds__(64) void snn_scan_wfr(const float* __restrict__ cur,
                                                   float* __restrict__ mp_out,
                                                   float* __restrict__ states,
                                                   int* __restrict__ flags) {
#pragma clang fp contract(off)
    __shared__ float smp[CSTEPS * EXPERTS];   // 64 KB
    const int e = threadIdx.x;
    const int w = blockIdx.x;
    const float* cbase = cur + (long)w * CSTEPS * EXPERTS + e;

    for (int k = 1; k <= KITER; ++k) {
        float mp = 0.0f, refr = 0.0f;
        if (w > 0 && k > 1) {
            const int s = (k - 2) * NCHUNK + (w - 1);
            if (e == 0) {
                while (__hip_atomic_load(&flags[s], __ATOMIC_ACQUIRE, __HIP_MEMORY_SCOPE_AGENT) == 0)
                    __builtin_amdgcn_s_sleep(8);
            }
            __threadfence();
            mp   = __hip_atomic_load(&states[s * 2 * EXPERTS + e], __ATOMIC_RELAXED, __HIP_MEMORY_SCOPE_AGENT);
            refr = __hip_atomic_load(&states[s * 2 * EXPERTS + EXPERTS + e], __ATOMIC_RELAXED, __HIP_MEMORY_SCOPE_AGENT);
        }

        float ca[PF], cb[PF];
#pragma unroll
        for (int j = 0; j < PF; ++j) ca[j] = cbase[j * EXPERTS] * 0.1f;

        for (int t0 = 0; t0 < CSTEPS; t0 += 2 * PF) {
#pragma unroll
            for (int j = 0; j < PF; ++j) cb[j] = cbase[(t0 + PF + j) * EXPERTS] * 0.1f;
#pragma unroll
            for (int j = 0; j < PF; ++j) {
                const float term   = (refr <= 0.0f) ? ca[j] : 0.0f;
                const float mp_pre = mp * 0.9f + term;
                smp[(t0 + j) * EXPERTS + e] = mp_pre;
                const bool spike = mp_pre > 1.0f;
                mp = spike ? 0.0f : mp_pre;
                const float rdec = fmaxf(refr - 0.1f, 0.0f);
                refr = spike ? 1.0f : rdec;
            }
            if (t0 + 2 * PF < CSTEPS) {
#pragma unroll
                for (int j = 0; j < PF; ++j) ca[j] = cbase[(t0 + 2 * PF + j) * EXPERTS] * 0.1f;
            }
#pragma unroll
            for (int j = 0; j < PF; ++j) {
                const float term   = (refr <= 0.0f) ? cb[j] : 0.0f;
                const float mp_pre = mp * 0.9f + term;
                smp[(t0 + PF + j) * EXPERTS + e] = mp_pre;
                const bool spike = mp_pre > 1.0f;
                mp = spike ? 0.0f : mp_pre;
                const float rdec = fmaxf(refr - 0.1f, 0.0f);
                refr = spike ? 1.0f : rdec;
            }
        }

        if (k < KITER && w < NCHUNK - 1) {
            const int s2 = (k - 1) * NCHUNK + w;
            __hip_atomic_store(&states[s2 * 2 * EXPERTS + e], mp, __ATOMIC_RELAXED, __HIP_MEMORY_SCOPE_AGENT);
            __hip_atomic_store(&states[s2 * 2 * EXPERTS + EXPERTS + e], refr, __ATOMIC_RELAXED, __HIP_MEMORY_SCOPE_AGENT);
            __threadfence();
            if (e == 0)
                __hip_atomic_store(&flags[s2], 1, __ATOMIC_RELEASE, __HIP_MEMORY_SCOPE_AGENT);
        }
    }

    float4* o4 = reinterpret_cast<float4*>(mp_out + (long)w * CSTEPS * EXPERTS);
    const float4* s4 = reinterpret_cast<const float4*>(smp);
#pragma unroll 4
    for (int i = threadIdx.x; i < CSTEPS * EXPERTS / 4; i += 64)
        o4[i] = s4[i];
}

// ================= Routing softmax (in-place on d_out) =================
__global__ __launch_bounds__(256) void snn_softmax(float* __restrict__ io) {
    const int  lane = threadIdx.x & 63;
    const int  wv   = threadIdx.x >> 6;
    const long t    = (long)blockIdx.x * 4 + wv;

    const float v = io[t * EXPERTS + lane];
    const bool spike = v > 1.0f;
    const unsigned long long ball = __ballot(spike);

    float out;
    if (ball != 0ull) {
        const int   n   = __popcll(ball);
        const float em1 = expf(-1.0f);
        const float denom = (float)n + (float)(EXPERTS - n) * em1;
        out = spike ? (1.0f / denom) : (em1 / denom);
    } else {
        float m = v;
#pragma unroll
        for (int off = 32; off >= 1; off >>= 1)
            m = fmaxf(m, __shfl_xor(m, off, 64));
        const float p = expf(v - m);
        float s = p;
#pragma unroll
        for (int off = 32; off >= 1; off >>= 1)
            s += __shfl_xor(s, off, 64);
        out = p / s;
    }
    io[t * EXPERTS + lane] = out;
}

// ---------------------------------------------------------------------------
extern "C" void kernel_launch(void* const* d_in, const int* in_sizes, int n_in,
                              void* d_out, int out_size, void* d_ws, size_t ws_size,
                              hipStream_t stream) {
    const float* hs = (const float*)d_in[0];   // [4,2048,2048] f32
    const float* w  = (const float*)d_in[1];   // [2048,64] f32
    float* out = (float*)d_out;                // [4,2048,64] f32

    char*  ws     = (char*)d_ws;
    int*   flags  = (int*)ws;                          // 4 KB
    float* states = (float*)(ws + 4096);               // 64 KB
    float* cur    = (float*)(ws + (1u << 20));         // 2 MB @ 1 MB
    float* part   = (float*)(ws + (4u << 20));         // up to 8 x 2 MB @ 4 MB

    const size_t slab = (size_t)T_TOTAL * EXPERTS * sizeof(float);   // 2 MB
    hipMemsetAsync(flags, 0, 4096, stream);

    if (ws_size >= (4u << 20) + 8 * slab) {
        snn_gemm_sk<HIDDEN / 8><<<dim3(T_TOTAL / BM, 8), dim3(256), 0, stream>>>(hs, w, part);
        snn_combine<<<dim3(T_TOTAL * EXPERTS / 4 / 256), dim3(256), 0, stream>>>(part, cur, 8);
    } else if (ws_size >= (4u << 20) + 4 * slab) {
        snn_gemm_sk<HIDDEN / 4><<<dim3(T_TOTAL / BM, 4), dim3(256), 0, stream>>>(hs, w, part);
        snn_combine<<<dim3(T_TOTAL * EXPERTS / 4 / 256), dim3(256), 0, stream>>>(part, cur, 4);
    } else {
        snn_gemm_sk<HIDDEN><<<dim3(T_TOTAL / BM, 1), dim3(256), 0, stream>>>(hs, w, cur);
    }
    snn_scan_wfr<<<dim3(NCHUNK), dim3(64), 0, stream>>>(cur, out, states, flags);
    snn_softmax<<<dim3(T_TOTAL / 4), dim3(256), 0, stream>>>(out);
}